// Round 2
// baseline (439.488 us; speedup 1.0000x reference)
//
#include <hip/hip_runtime.h>

#define MARGIN   0.3f
#define S_SCALE  15.0f
#define LAMDA    2.0f
#define NB       8192
#define NC       10000
#define LOG2E    1.4426950408889634f
#define K2       (S_SCALE * LOG2E)     // 21.6404256...
#define B2       (-S_SCALE * LOG2E)    // fixed shift: logits in [0,15], subtract 15

// One block (256 thr) per row. All 10 float4 loads issued up-front for max
// memory-level parallelism; 4 independent accumulators; raw v_exp_f32.
// exp(15*x - 15) == exp2(K2*x + B2).
__global__ __launch_bounds__(256) void dam_row_loss(const float* __restrict__ costh,
                                                    const int* __restrict__ label,
                                                    float* __restrict__ out) {
    const int row = blockIdx.x;
    const int tid = threadIdx.x;
    const float* __restrict__ rowp = costh + (size_t)row * NC;
    const float4* __restrict__ rp4 = (const float4*)rowp;   // 40000 B rows, 16B aligned

    // 2500 float4 per row = 9 full strides of 256 + tail of 196
    float4 v[10];
    #pragma unroll
    for (int j = 0; j < 9; ++j) v[j] = rp4[tid + 256 * j];
    v[9] = make_float4(-INFINITY, -INFINITY, -INFINITY, -INFINITY);  // exp2 -> 0
    if (tid < 196) v[9] = rp4[2304 + tid];

    float s0 = 0.f, s1 = 0.f, s2 = 0.f, s3 = 0.f;
    #pragma unroll
    for (int j = 0; j < 10; ++j) {
        s0 += __builtin_amdgcn_exp2f(fmaf(K2, v[j].x, B2));
        s1 += __builtin_amdgcn_exp2f(fmaf(K2, v[j].y, B2));
        s2 += __builtin_amdgcn_exp2f(fmaf(K2, v[j].z, B2));
        s3 += __builtin_amdgcn_exp2f(fmaf(K2, v[j].w, B2));
    }
    float s = (s0 + s1) + (s2 + s3);

    // wave64 butterfly-free shuffle reduce, then across the 4 waves via LDS
    #pragma unroll
    for (int off = 32; off > 0; off >>= 1)
        s += __shfl_down(s, off, 64);
    __shared__ float wsum[4];
    if ((tid & 63) == 0) wsum[tid >> 6] = s;
    __syncthreads();

    if (tid == 0) {
        float tot = (wsum[0] + wsum[1]) + (wsum[2] + wsum[3]);
        const int lbl = label[row];
        const float cos_t = rowp[lbl];
        const float delta = (MARGIN / LAMDA) * __expf(1.0f - cos_t);
        const float t_logit = S_SCALE * (cos_t - delta);     // margin-adjusted target logit
        // swap original target term for the adjusted one (both with the -15 shift)
        tot += __builtin_amdgcn_exp2f(fmaf(LOG2E, t_logit, B2))
             - __builtin_amdgcn_exp2f(fmaf(K2, cos_t, B2));
        const float lse = S_SCALE + __logf(tot);
        atomicAdd(out, (lse - t_logit) * (1.0f / (float)NB));  // -logp[target]/NB
    }
}

extern "C" void kernel_launch(void* const* d_in, const int* in_sizes, int n_in,
                              void* d_out, int out_size, void* d_ws, size_t ws_size,
                              hipStream_t stream) {
    const float* costh = (const float*)d_in[0];
    const int*   label = (const int*)d_in[1];
    float* out = (float*)d_out;

    // d_out is re-poisoned to 0xAA before every launch; zero it for the atomics.
    hipMemsetAsync(out, 0, sizeof(float), stream);
    dam_row_loss<<<NB, 256, 0, stream>>>(costh, label, out);
}